// Round 1
// 634.232 us; speedup vs baseline: 1.0975x; 1.0975x over previous
//
#include <hip/hip_runtime.h>

#define B_ 8
#define S_ 1024
#define H_ 1024
#define NH_ 4
#define D_ 256
#define M_ 8192

typedef unsigned int u32;
typedef unsigned short u16;
typedef __attribute__((ext_vector_type(4))) float f32x4;
typedef __attribute__((ext_vector_type(8))) short s16x8;

__device__ __forceinline__ float bf2f(u16 b) { return __uint_as_float(((u32)b) << 16); }
__device__ __forceinline__ u16 f2bf(float f) {
    u32 x = __float_as_uint(f);
    return (u16)((x + 0x7fffu + ((x >> 16) & 1u)) >> 16);   // RNE
}

// ---------------- mask dtype detection ----------------
__global__ void init_flags_k(int* fl) { fl[0] = 0; fl[1] = 0; fl[2] = 0; }

__global__ __launch_bounds__(256) void or_mask_k(const u32* __restrict__ m, int* __restrict__ fl) {
    u32 v = m[blockIdx.x * 256 + threadIdx.x];   // first 256 KiB: in range for every encoding
#pragma unroll
    for (int o = 32; o; o >>= 1) v |= __shfl_xor(v, o, 64);
    if ((threadIdx.x & 63) == 0) atomicOr(fl + 1, (int)v);
}

__global__ void classify_mask_k(int* fl) {
    u32 R = (u32)fl[1];
    int c;
    if (R == 0x3F803F80u)      c = 2;  // bf16 {0,1}
    else if (R == 0x3F800000u) c = 3;  // fp32 {0,1}
    else if (R & 0xFFFFFF00u)  c = 0;  // u8 bool
    else                       c = 1;  // int32
    fl[2] = c;
}

// ---------------- transpose-cast: dst[c][r] (bf16) = src[r][c] (fp32) ----------------
__global__ __launch_bounds__(256) void tcast_k(const float* __restrict__ src, u16* __restrict__ dst,
                                               int R, int C) {
    __shared__ float sb[32][33];
    const int c0 = blockIdx.x * 32, r0 = blockIdx.y * 32;
    const int tx = threadIdx.x & 31, ty = threadIdx.x >> 5;   // ty in [0,8)
#pragma unroll
    for (int i = 0; i < 4; i++)
        sb[ty + 8 * i][tx] = src[(size_t)(r0 + ty + 8 * i) * C + c0 + tx];
    __syncthreads();
#pragma unroll
    for (int i = 0; i < 4; i++)
        dst[(size_t)(c0 + ty + 8 * i) * R + r0 + tx] = f2bf(sb[tx][ty + 8 * i]);
}

// ---------------- plain cast fp32 -> bf16 (row-major) ----------------
__global__ __launch_bounds__(256) void castbf_k(const float* __restrict__ src, u16* __restrict__ dst) {
    const int i = blockIdx.x * 256 + threadIdx.x;
    float4 v = ((const float4*)src)[i];
    ushort4 o;
    o.x = f2bf(v.x); o.y = f2bf(v.y); o.z = f2bf(v.z); o.w = f2bf(v.w);
    ((ushort4*)dst)[i] = o;
}

// ---------------- MFMA GEMM core: C(128x128 tile) = A[m][k] * B[n][k]^T ----------------
// AMODE: 0 = A fp32, 1 = A bf16, 2 = concat (k<1024: fp32 A32; k>=1024: bf16 A16)
template<int AMODE>
__device__ __forceinline__ void gemm_core(
    const float* __restrict__ A32, const u16* __restrict__ A16, int lda,
    const u16* __restrict__ Bp, int ldb, int K, int m0, int n0,
    short* As, short* Bs, f32x4 acc[4][4])
{
    const int t = threadIdx.x;
    const int lane = t & 63, wave = t >> 6;
    const int wy = wave >> 1, wx = wave & 1;
    const int mq = lane >> 4, ml = lane & 15;
    const int srow = t >> 2, skq = t & 3;

    for (int k0 = 0; k0 < K; k0 += 32) {
        __syncthreads();
        // stage A-tile: 128 rows x 32 k (bf16, row stride 40)
#pragma unroll
        for (int it = 0; it < 2; it++) {
            const int row = srow + it * 64;
            const int kk = k0 + skq * 8;
            short* dst = As + row * 40 + skq * 8;
            if (AMODE == 0) {
                const float* s = A32 + (size_t)(m0 + row) * lda + kk;
                float4 v0 = *(const float4*)s, v1 = *(const float4*)(s + 4);
                s16x8 p;
                p[0] = (short)f2bf(v0.x); p[1] = (short)f2bf(v0.y);
                p[2] = (short)f2bf(v0.z); p[3] = (short)f2bf(v0.w);
                p[4] = (short)f2bf(v1.x); p[5] = (short)f2bf(v1.y);
                p[6] = (short)f2bf(v1.z); p[7] = (short)f2bf(v1.w);
                *(s16x8*)dst = p;
            } else if (AMODE == 1) {
                *(s16x8*)dst = *(const s16x8*)(A16 + (size_t)(m0 + row) * lda + kk);
            } else {
                if (kk < 1024) {
                    const float* s = A32 + (size_t)(m0 + row) * 1024 + kk;
                    float4 v0 = *(const float4*)s, v1 = *(const float4*)(s + 4);
                    s16x8 p;
                    p[0] = (short)f2bf(v0.x); p[1] = (short)f2bf(v0.y);
                    p[2] = (short)f2bf(v0.z); p[3] = (short)f2bf(v0.w);
                    p[4] = (short)f2bf(v1.x); p[5] = (short)f2bf(v1.y);
                    p[6] = (short)f2bf(v1.z); p[7] = (short)f2bf(v1.w);
                    *(s16x8*)dst = p;
                } else {
                    *(s16x8*)dst = *(const s16x8*)(A16 + (size_t)(m0 + row) * 1024 + (kk - 1024));
                }
            }
        }
        // stage B-tile: 128 rows (n) x 32 k (bf16)
#pragma unroll
        for (int it = 0; it < 2; it++) {
            const int row = srow + it * 64;
            *(s16x8*)(Bs + row * 40 + skq * 8) =
                *(const s16x8*)(Bp + (size_t)(n0 + row) * ldb + k0 + skq * 8);
        }
        __syncthreads();
        s16x8 af[4], bfr[4];
#pragma unroll
        for (int i = 0; i < 4; i++) {
            af[i]  = *(s16x8*)(As + (wy * 64 + i * 16 + ml) * 40 + mq * 8);
            bfr[i] = *(s16x8*)(Bs + (wx * 64 + i * 16 + ml) * 40 + mq * 8);
        }
#pragma unroll
        for (int mi = 0; mi < 4; mi++)
#pragma unroll
            for (int ni = 0; ni < 4; ni++)
                acc[mi][ni] = __builtin_amdgcn_mfma_f32_16x16x32_bf16(af[mi], bfr[ni], acc[mi][ni], 0, 0, 0);
    }
}

// ---------------- QKV projection: C[m][n] bf16 = A(bf16) @ WT(bf16)^T ----------------
__global__ __launch_bounds__(256) void gemm_proj_k(const u16* __restrict__ A, const u16* __restrict__ WT,
                                                   u16* __restrict__ C) {
    __shared__ short As[128 * 40];
    __shared__ short Bs[128 * 40];
    const int m0 = blockIdx.y * 128, n0 = blockIdx.x * 128;
    f32x4 acc[4][4];
#pragma unroll
    for (int i = 0; i < 4; i++)
#pragma unroll
        for (int j = 0; j < 4; j++) acc[i][j] = 0;
    gemm_core<1>(nullptr, A, H_, WT, H_, H_, m0, n0, As, Bs, acc);
    const int lane = threadIdx.x & 63, wave = threadIdx.x >> 6;
    const int wy = wave >> 1, wx = wave & 1, mq = lane >> 4, ml = lane & 15;
#pragma unroll
    for (int mi = 0; mi < 4; mi++)
#pragma unroll
        for (int ni = 0; ni < 4; ni++) {
            const int n = n0 + wx * 64 + ni * 16 + ml;
#pragma unroll
            for (int r = 0; r < 4; r++) {
                const int m = m0 + wy * 64 + mi * 16 + mq * 4 + r;
                C[(size_t)m * H_ + n] = f2bf(acc[mi][ni][r]);
            }
        }
}

// ---------------- V projection with transposed store: VT[b*1024 + n][s] ----------------
__global__ __launch_bounds__(256) void gemm_vt_k(const u16* __restrict__ A, const u16* __restrict__ WT,
                                                 u16* __restrict__ VT) {
    __shared__ short As[128 * 40];
    __shared__ short Bs[128 * 40];
    const int m0 = blockIdx.y * 128, n0 = blockIdx.x * 128;
    f32x4 acc[4][4];
#pragma unroll
    for (int i = 0; i < 4; i++)
#pragma unroll
        for (int j = 0; j < 4; j++) acc[i][j] = 0;
    gemm_core<1>(nullptr, A, H_, WT, H_, H_, m0, n0, As, Bs, acc);
    const int lane = threadIdx.x & 63, wave = threadIdx.x >> 6;
    const int wy = wave >> 1, wx = wave & 1, mq = lane >> 4, ml = lane & 15;
#pragma unroll
    for (int mi = 0; mi < 4; mi++)
#pragma unroll
        for (int ni = 0; ni < 4; ni++) {
            const int n = n0 + wx * 64 + ni * 16 + ml;
            const int mbase = m0 + wy * 64 + mi * 16 + mq * 4;   // 4-aligned, same b for all 4
            const int b = mbase >> 10, s = mbase & 1023;
            ushort4 w;
            w.x = f2bf(acc[mi][ni][0]); w.y = f2bf(acc[mi][ni][1]);
            w.z = f2bf(acc[mi][ni][2]); w.w = f2bf(acc[mi][ni][3]);
            *(ushort4*)(VT + ((size_t)(b * 1024 + n)) * 1024 + s) = w;
        }
}

// ---------------- FUSED QK^T + gauss + mask + softmax + query_mask -> final attn fp32 ----------------
// Block: 64 q-rows x full 1024 k-cols. 512 threads = 8 waves (2m x 4n); wave tile 32m x 256n.
// acc[mi in 0..1][nf in 0..15]: row = m0 + wm*32 + mi*16 + mq*4 + r, col = wn*256 + nf*16 + ml.
__global__ __launch_bounds__(512, 2) void qk_sm_k(
    const u16* __restrict__ Qb, const u16* __restrict__ Kb,
    const void* __restrict__ mask, const float* __restrict__ gfac,
    const int* __restrict__ fl, const float* __restrict__ qmask,
    float* __restrict__ attn)
{
    __shared__ short Bs[1024 * 40];        // 80 KiB: 1024 k-rows x 32 k-slice
    __shared__ short As[64 * 40];          //  5 KiB: 64 q-rows x 32 k-slice
    __shared__ float red[2][32][4];        //  1 KiB: cross-wave row reductions

    // XCD-bijective swizzle: 512 blocks, contiguous 64-block chunk (4 full z) per XCD
    const int flat = blockIdx.x;
    const int wgid = (flat & 7) * 64 + (flat >> 3);
    const int z = wgid >> 4, m0 = (wgid & 15) * 64;
    const int h = z >> 3, b = z & 7;

    const u16* Aq = Qb + (size_t)b * S_ * H_ + h * D_;
    const u16* Bk = Kb + (size_t)b * S_ * H_ + h * D_;

    const int t = threadIdx.x;
    const int lane = t & 63, wave = t >> 6;
    const int wm = wave >> 2, wn = wave & 3;
    const int mq = lane >> 4, ml = lane & 15;

    f32x4 acc[2][16];
#pragma unroll
    for (int mi = 0; mi < 2; mi++)
#pragma unroll
        for (int nf = 0; nf < 16; nf++) acc[mi][nf] = 0;

    for (int k0 = 0; k0 < D_; k0 += 32) {
        __syncthreads();
        if (t < 256) {                               // stage A: 64 rows x 32 k
            const int row = t >> 2, kq = t & 3;
            *(s16x8*)(As + row * 40 + kq * 8) =
                *(const s16x8*)(Aq + (size_t)(m0 + row) * H_ + k0 + kq * 8);
        }
#pragma unroll
        for (int it = 0; it < 8; it++) {             // stage B: 1024 rows x 32 k
            const int c = it * 512 + t;
            const int row = c >> 2, kq = c & 3;
            *(s16x8*)(Bs + row * 40 + kq * 8) =
                *(const s16x8*)(Bk + (size_t)row * H_ + k0 + kq * 8);
        }
        __syncthreads();
        s16x8 af0 = *(s16x8*)(As + (wm * 32 + ml) * 40 + mq * 8);
        s16x8 af1 = *(s16x8*)(As + (wm * 32 + 16 + ml) * 40 + mq * 8);
#pragma unroll
        for (int g4 = 0; g4 < 4; g4++) {
            s16x8 bf4[4];
#pragma unroll
            for (int j = 0; j < 4; j++)
                bf4[j] = *(s16x8*)(Bs + (wn * 256 + (g4 * 4 + j) * 16 + ml) * 40 + mq * 8);
#pragma unroll
            for (int j = 0; j < 4; j++) {
                acc[0][g4 * 4 + j] = __builtin_amdgcn_mfma_f32_16x16x32_bf16(af0, bf4[j], acc[0][g4 * 4 + j], 0, 0, 0);
                acc[1][g4 * 4 + j] = __builtin_amdgcn_mfma_f32_16x16x32_bf16(af1, bf4[j], acc[1][g4 * 4 + j], 0, 0, 0);
            }
        }
    }

    // ---- epilogue: gauss + mask + online stats, all on register fragments ----
    const float ginv = 1.0f / gfac[0];
    const int code = fl[2];
    const size_t zrow = (size_t)z * S_;
    float rmax[2][4], rsum[2][4], scv[2][4];

#pragma unroll
    for (int mi = 0; mi < 2; mi++)
#pragma unroll
        for (int r = 0; r < 4; r++) {
            const int qg = m0 + wm * 32 + mi * 16 + mq * 4 + r;
            const size_t mbase = ((size_t)b * S_ + qg) * S_;
            float mx = -3.0e38f;
#pragma unroll
            for (int nf = 0; nf < 16; nf++) {
                const int kg = wn * 256 + nf * 16 + ml;
                float diff = (float)(qg - kg);
                float val = acc[mi][nf][r] * 0.0625f - diff * diff * ginv;
                int mv;
                if (code == 0)      mv = ((const unsigned char*)mask)[mbase + kg];
                else if (code == 1) mv = ((const int*)mask)[mbase + kg];
                else if (code == 2) mv = (((const u16*)mask)[mbase + kg] != 0);
                else                mv = (((const u32*)mask)[mbase + kg] != 0);
                if (mv) val = -4294967296.0f;
                acc[mi][nf][r] = val;
                mx = fmaxf(mx, val);
            }
            rmax[mi][r] = mx;
        }
    // reduce max over the 16-lane (ml) group — lanes with same mq share the same rows
#pragma unroll
    for (int o = 1; o < 16; o <<= 1)
#pragma unroll
        for (int mi = 0; mi < 2; mi++)
#pragma unroll
            for (int r = 0; r < 4; r++)
                rmax[mi][r] = fmaxf(rmax[mi][r], __shfl_xor(rmax[mi][r], o, 64));
    if (ml == 0)
#pragma unroll
        for (int mi = 0; mi < 2; mi++)
#pragma unroll
            for (int r = 0; r < 4; r++) red[wm][mi * 16 + mq * 4 + r][wn] = rmax[mi][r];
    __syncthreads();
#pragma unroll
    for (int mi = 0; mi < 2; mi++)
#pragma unroll
        for (int r = 0; r < 4; r++) {
            const int rr = mi * 16 + mq * 4 + r;
            rmax[mi][r] = fmaxf(fmaxf(red[wm][rr][0], red[wm][rr][1]),
                                fmaxf(red[wm][rr][2], red[wm][rr][3]));
        }
    __syncthreads();
    // exp + sum
#pragma unroll
    for (int mi = 0; mi < 2; mi++)
#pragma unroll
        for (int r = 0; r < 4; r++) {
            float s = 0.f;
#pragma unroll
            for (int nf = 0; nf < 16; nf++) {
                float p = __expf(acc[mi][nf][r] - rmax[mi][r]);
                acc[mi][nf][r] = p;
                s += p;
            }
            rsum[mi][r] = s;
        }
#pragma unroll
    for (int o = 1; o < 16; o <<= 1)
#pragma unroll
        for (int mi = 0; mi < 2; mi++)
#pragma unroll
            for (int r = 0; r < 4; r++) rsum[mi][r] += __shfl_xor(rsum[mi][r], o, 64);
    if (ml == 0)
#pragma unroll
        for (int mi = 0; mi < 2; mi++)
#pragma unroll
            for (int r = 0; r < 4; r++) red[wm][mi * 16 + mq * 4 + r][wn] = rsum[mi][r];
    __syncthreads();
#pragma unroll
    for (int mi = 0; mi < 2; mi++)
#pragma unroll
        for (int r = 0; r < 4; r++) {
            const int rr = mi * 16 + mq * 4 + r;
            const int qg = m0 + wm * 32 + mi * 16 + mq * 4 + r;
            const float s = red[wm][rr][0] + red[wm][rr][1] + red[wm][rr][2] + red[wm][rr][3];
            scv[mi][r] = qmask[b * S_ + qg] / s;
        }
    // store final attn (qmask-scaled)
#pragma unroll
    for (int mi = 0; mi < 2; mi++)
#pragma unroll
        for (int r = 0; r < 4; r++) {
            const int qg = m0 + wm * 32 + mi * 16 + mq * 4 + r;
            float* prow = attn + (zrow + qg) * S_ + wn * 256 + ml;
            const float sc = scv[mi][r];
#pragma unroll
            for (int nf = 0; nf < 16; nf++)
                prow[nf * 16] = acc[mi][nf][r] * sc;
        }
}

// ---------------- PV: res[b*S+m][h*D + n] bf16 = attn(fp32) @ VT^T ----------------
__global__ __launch_bounds__(256) void pv_mfma_k(const float* __restrict__ attnF, const u16* __restrict__ VT,
                                                 u16* __restrict__ resB) {
    __shared__ short As[128 * 40];
    __shared__ short Bs[128 * 40];
    const int z = blockIdx.z, h = z >> 3, b = z & 7;
    const float* Ap = attnF + (size_t)z * S_ * S_;
    const u16* Bp = VT + ((size_t)(b * 1024 + h * D_)) * 1024;
    const int m0 = blockIdx.y * 128, n0 = blockIdx.x * 128;   // n0 in {0,128}
    f32x4 acc[4][4];
#pragma unroll
    for (int i = 0; i < 4; i++)
#pragma unroll
        for (int j = 0; j < 4; j++) acc[i][j] = 0;
    gemm_core<0>(Ap, nullptr, S_, Bp, 1024, S_, m0, n0, As, Bs, acc);
    u16* C = resB + (size_t)b * S_ * H_ + h * D_;
    const int lane = threadIdx.x & 63, wave = threadIdx.x >> 6;
    const int wy = wave >> 1, wx = wave & 1, mq = lane >> 4, ml = lane & 15;
#pragma unroll
    for (int mi = 0; mi < 4; mi++)
#pragma unroll
        for (int ni = 0; ni < 4; ni++) {
            const int n = n0 + wx * 64 + ni * 16 + ml;
#pragma unroll
            for (int r = 0; r < 4; r++) {
                const int m = m0 + wy * 64 + mi * 16 + mq * 4 + r;
                C[(size_t)m * H_ + n] = f2bf(acc[mi][ni][r]);
            }
        }
}

// ---------------- final: tmp[m][n] bf16 = [dec|res] @ WfT^T + bf + dec ----------------
__global__ __launch_bounds__(256) void final_mfma_k(const float* __restrict__ dec, const u16* __restrict__ resB,
                                                    const u16* __restrict__ WfT, const float* __restrict__ bfv,
                                                    u16* __restrict__ tmp) {
    __shared__ short As[128 * 40];
    __shared__ short Bs[128 * 40];
    const int m0 = blockIdx.y * 128, n0 = blockIdx.x * 128;
    f32x4 acc[4][4];
#pragma unroll
    for (int i = 0; i < 4; i++)
#pragma unroll
        for (int j = 0; j < 4; j++) acc[i][j] = 0;
    gemm_core<2>(dec, resB, H_, WfT, 2048, 2048, m0, n0, As, Bs, acc);
    const int lane = threadIdx.x & 63, wave = threadIdx.x >> 6;
    const int wy = wave >> 1, wx = wave & 1, mq = lane >> 4, ml = lane & 15;
#pragma unroll
    for (int mi = 0; mi < 4; mi++)
#pragma unroll
        for (int ni = 0; ni < 4; ni++) {
            const int n = n0 + wx * 64 + ni * 16 + ml;
#pragma unroll
            for (int r = 0; r < 4; r++) {
                const int m = m0 + wy * 64 + mi * 16 + mq * 4 + r;
                float val = acc[mi][ni][r] + bfv[n] + dec[(size_t)m * H_ + n];
                tmp[(size_t)m * H_ + n] = f2bf(val);
            }
        }
}

// ---------------- LayerNorm (bf16 tmp -> fp32 out) ----------------
__global__ __launch_bounds__(256) void ln2_k(const u16* __restrict__ tmp, const float* __restrict__ gm,
                                             const float* __restrict__ bt, float* __restrict__ out) {
    const int m = blockIdx.x, t = threadIdx.x;
    ushort4 u = ((const ushort4*)(tmp + (size_t)m * H_))[t];
    float xa[4] = {bf2f(u.x), bf2f(u.y), bf2f(u.z), bf2f(u.w)};
    float s = 0.f, s2 = 0.f;
#pragma unroll
    for (int i = 0; i < 4; i++) { s += xa[i]; s2 += xa[i] * xa[i]; }
#pragma unroll
    for (int o = 32; o; o >>= 1) { s += __shfl_xor(s, o, 64); s2 += __shfl_xor(s2, o, 64); }
    __shared__ float rs[4], rs2[4];
    if ((t & 63) == 0) { rs[t >> 6] = s; rs2[t >> 6] = s2; }
    __syncthreads();
    s  = rs[0] + rs[1] + rs[2] + rs[3];
    s2 = rs2[0] + rs2[1] + rs2[2] + rs2[3];
    float mu = s * (1.f / 1024.f);
    float var = s2 * (1.f / 1024.f) - mu * mu;
    float rstd = rsqrtf(var + 1e-5f);
    float ov[4];
#pragma unroll
    for (int i = 0; i < 4; i++) {
        int n = t * 4 + i;
        ov[i] = (xa[i] - mu) * rstd * gm[n] + bt[n];
    }
    *(float4*)(out + (size_t)m * H_ + t * 4) = make_float4(ov[0], ov[1], ov[2], ov[3]);
}

extern "C" void kernel_launch(void* const* d_in, const int* in_sizes, int n_in,
                              void* d_out, int out_size, void* d_ws, size_t ws_size,
                              hipStream_t stream) {
    const float* memory = (const float*)d_in[0];
    const float* dec    = (const float*)d_in[1];
    const void*  mask   = d_in[2];
    const float* qmask  = (const float*)d_in[3];
    const float* Wk     = (const float*)d_in[4];
    const float* Wv     = (const float*)d_in[5];
    const float* Wq     = (const float*)d_in[6];
    const float* Wf     = (const float*)d_in[7];
    const float* bfv    = (const float*)d_in[8];
    const float* gamma  = (const float*)d_in[9];
    const float* beta   = (const float*)d_in[10];
    const float* gfac   = (const float*)d_in[11];

    // ---- workspace layout (peak 59 MiB) ----
    // [0,1M) flags | [1,3) WqT | [3,5) WkT | [5,7) WvT | [7,11) WfT
    // [11,27) Qb bf16  (tmp bf16 aliases after attn)
    // [27,43) Kb bf16  (resB aliases after attn)
    // [43,59) VT bf16
    char* ws = (char*)d_ws;
    int* fl  = (int*)ws;
    u16* WqT = (u16*)(ws + (1u  << 20));
    u16* WkT = (u16*)(ws + (3u  << 20));
    u16* WvT = (u16*)(ws + (5u  << 20));
    u16* WfT = (u16*)(ws + (7u  << 20));
    u16* Qb  = (u16*)(ws + (11u << 20));
    u16* Kb  = (u16*)(ws + (27u << 20));
    u16* VT  = (u16*)(ws + (43u << 20));
    u16* resB = Kb;          // Kb dead after qk_sm_k
    u16* tmpB = Qb;          // Qb dead after qk_sm_k

    float* out   = (float*)d_out;
    float* attnF = out + (size_t)B_ * S_ * H_;   // final attn written once by qk_sm_k

    // bf16 pre-casts live in the attn region of d_out (dead once qk_sm_k writes attn)
    u16* memB = (u16*)attnF;
    u16* decB = memB + (size_t)B_ * S_ * H_;

    init_flags_k<<<1, 1, 0, stream>>>(fl);
    or_mask_k<<<256, 256, 0, stream>>>((const u32*)mask, fl);
    classify_mask_k<<<1, 1, 0, stream>>>(fl);

    tcast_k<<<dim3(32, 32), 256, 0, stream>>>(Wq, WqT, 1024, 1024);
    tcast_k<<<dim3(32, 32), 256, 0, stream>>>(Wk, WkT, 1024, 1024);
    tcast_k<<<dim3(32, 32), 256, 0, stream>>>(Wv, WvT, 1024, 1024);
    tcast_k<<<dim3(32, 64), 256, 0, stream>>>(Wf, WfT, 2048, 1024);

    castbf_k<<<8192, 256, 0, stream>>>(memory, memB);
    castbf_k<<<8192, 256, 0, stream>>>(dec,    decB);

    gemm_proj_k<<<dim3(8, 64), 256, 0, stream>>>(decB, WqT, Qb);
    gemm_proj_k<<<dim3(8, 64), 256, 0, stream>>>(memB, WkT, Kb);
    gemm_vt_k  <<<dim3(8, 64), 256, 0, stream>>>(memB, WvT, VT);

    qk_sm_k<<<512, 512, 0, stream>>>(Qb, Kb, mask, gfac, fl, qmask, attnF);
    pv_mfma_k<<<dim3(2, 8, 32), 256, 0, stream>>>(attnF, VT, resB);
    final_mfma_k<<<dim3(8, 64), 256, 0, stream>>>(dec, resB, WfT, bfv, tmpB);
    ln2_k<<<M_, 256, 0, stream>>>(tmpB, gamma, beta, out);
}

// Round 2
// 616.670 us; speedup vs baseline: 1.1287x; 1.0285x over previous
//
#include <hip/hip_runtime.h>

#define B_ 8
#define S_ 1024
#define H_ 1024
#define NH_ 4
#define D_ 256
#define M_ 8192

typedef unsigned int u32;
typedef unsigned short u16;
typedef __attribute__((ext_vector_type(4))) float f32x4;
typedef __attribute__((ext_vector_type(8))) short s16x8;

__device__ __forceinline__ float bf2f(u16 b) { return __uint_as_float(((u32)b) << 16); }
__device__ __forceinline__ u16 f2bf(float f) {
    u32 x = __float_as_uint(f);
    return (u16)((x + 0x7fffu + ((x >> 16) & 1u)) >> 16);   // RNE
}

// ---------------- mask dtype detection ----------------
__global__ void init_flags_k(int* fl) { fl[0] = 0; fl[1] = 0; fl[2] = 0; }

__global__ __launch_bounds__(256) void or_mask_k(const u32* __restrict__ m, int* __restrict__ fl) {
    u32 v = m[blockIdx.x * 256 + threadIdx.x];   // first 256 KiB: in range for every encoding
#pragma unroll
    for (int o = 32; o; o >>= 1) v |= __shfl_xor(v, o, 64);
    if ((threadIdx.x & 63) == 0) atomicOr(fl + 1, (int)v);
}

__global__ void classify_mask_k(int* fl) {
    u32 R = (u32)fl[1];
    int c;
    if (R == 0x3F803F80u)      c = 2;  // bf16 {0,1}
    else if (R == 0x3F800000u) c = 3;  // fp32 {0,1}
    else if (R & 0xFFFFFF00u)  c = 0;  // u8 bool
    else                       c = 1;  // int32
    fl[2] = c;
}

// ---------------- transpose-cast: dst[c][r] (bf16) = src[r][c] (fp32) ----------------
__global__ __launch_bounds__(256) void tcast_k(const float* __restrict__ src, u16* __restrict__ dst,
                                               int R, int C) {
    __shared__ float sb[32][33];
    const int c0 = blockIdx.x * 32, r0 = blockIdx.y * 32;
    const int tx = threadIdx.x & 31, ty = threadIdx.x >> 5;   // ty in [0,8)
#pragma unroll
    for (int i = 0; i < 4; i++)
        sb[ty + 8 * i][tx] = src[(size_t)(r0 + ty + 8 * i) * C + c0 + tx];
    __syncthreads();
#pragma unroll
    for (int i = 0; i < 4; i++)
        dst[(size_t)(c0 + ty + 8 * i) * R + r0 + tx] = f2bf(sb[tx][ty + 8 * i]);
}

// ---------------- plain cast fp32 -> bf16 (row-major) ----------------
__global__ __launch_bounds__(256) void castbf_k(const float* __restrict__ src, u16* __restrict__ dst) {
    const int i = blockIdx.x * 256 + threadIdx.x;
    float4 v = ((const float4*)src)[i];
    ushort4 o;
    o.x = f2bf(v.x); o.y = f2bf(v.y); o.z = f2bf(v.z); o.w = f2bf(v.w);
    ((ushort4*)dst)[i] = o;
}

// ---------------- MFMA GEMM core: C(128x128 tile) = A[m][k] * B[n][k]^T ----------------
// AMODE: 1 = A bf16, 2 = concat (k<1024: fp32 A32; k>=1024: bf16 A16)
template<int AMODE>
__device__ __forceinline__ void gemm_core(
    const float* __restrict__ A32, const u16* __restrict__ A16, int lda,
    const u16* __restrict__ Bp, int ldb, int K, int m0, int n0,
    short* As, short* Bs, f32x4 acc[4][4])
{
    const int t = threadIdx.x;
    const int lane = t & 63, wave = t >> 6;
    const int wy = wave >> 1, wx = wave & 1;
    const int mq = lane >> 4, ml = lane & 15;
    const int srow = t >> 2, skq = t & 3;

    for (int k0 = 0; k0 < K; k0 += 32) {
        __syncthreads();
        // stage A-tile: 128 rows x 32 k (bf16, row stride 40)
#pragma unroll
        for (int it = 0; it < 2; it++) {
            const int row = srow + it * 64;
            const int kk = k0 + skq * 8;
            short* dst = As + row * 40 + skq * 8;
            if (AMODE == 1) {
                *(s16x8*)dst = *(const s16x8*)(A16 + (size_t)(m0 + row) * lda + kk);
            } else {
                if (kk < 1024) {
                    const float* s = A32 + (size_t)(m0 + row) * 1024 + kk;
                    float4 v0 = *(const float4*)s, v1 = *(const float4*)(s + 4);
                    s16x8 p;
                    p[0] = (short)f2bf(v0.x); p[1] = (short)f2bf(v0.y);
                    p[2] = (short)f2bf(v0.z); p[3] = (short)f2bf(v0.w);
                    p[4] = (short)f2bf(v1.x); p[5] = (short)f2bf(v1.y);
                    p[6] = (short)f2bf(v1.z); p[7] = (short)f2bf(v1.w);
                    *(s16x8*)dst = p;
                } else {
                    *(s16x8*)dst = *(const s16x8*)(A16 + (size_t)(m0 + row) * 1024 + (kk - 1024));
                }
            }
        }
        // stage B-tile: 128 rows (n) x 32 k (bf16)
#pragma unroll
        for (int it = 0; it < 2; it++) {
            const int row = srow + it * 64;
            *(s16x8*)(Bs + row * 40 + skq * 8) =
                *(const s16x8*)(Bp + (size_t)(n0 + row) * ldb + k0 + skq * 8);
        }
        __syncthreads();
        s16x8 af[4], bfr[4];
#pragma unroll
        for (int i = 0; i < 4; i++) {
            af[i]  = *(s16x8*)(As + (wy * 64 + i * 16 + ml) * 40 + mq * 8);
            bfr[i] = *(s16x8*)(Bs + (wx * 64 + i * 16 + ml) * 40 + mq * 8);
        }
#pragma unroll
        for (int mi = 0; mi < 4; mi++)
#pragma unroll
            for (int ni = 0; ni < 4; ni++)
                acc[mi][ni] = __builtin_amdgcn_mfma_f32_16x16x32_bf16(af[mi], bfr[ni], acc[mi][ni], 0, 0, 0);
    }
}

// ---------------- QKV projection: C[m][n] bf16 = A(bf16) @ WT(bf16)^T ----------------
__global__ __launch_bounds__(256) void gemm_proj_k(const u16* __restrict__ A, const u16* __restrict__ WT,
                                                   u16* __restrict__ C) {
    __shared__ short As[128 * 40];
    __shared__ short Bs[128 * 40];
    const int m0 = blockIdx.y * 128, n0 = blockIdx.x * 128;
    f32x4 acc[4][4];
#pragma unroll
    for (int i = 0; i < 4; i++)
#pragma unroll
        for (int j = 0; j < 4; j++) acc[i][j] = 0;
    gemm_core<1>(nullptr, A, H_, WT, H_, H_, m0, n0, As, Bs, acc);
    const int lane = threadIdx.x & 63, wave = threadIdx.x >> 6;
    const int wy = wave >> 1, wx = wave & 1, mq = lane >> 4, ml = lane & 15;
#pragma unroll
    for (int mi = 0; mi < 4; mi++)
#pragma unroll
        for (int ni = 0; ni < 4; ni++) {
            const int n = n0 + wx * 64 + ni * 16 + ml;
#pragma unroll
            for (int r = 0; r < 4; r++) {
                const int m = m0 + wy * 64 + mi * 16 + mq * 4 + r;
                C[(size_t)m * H_ + n] = f2bf(acc[mi][ni][r]);
            }
        }
}

// ---------------- V projection with transposed store: VT[b*1024 + n][s] ----------------
__global__ __launch_bounds__(256) void gemm_vt_k(const u16* __restrict__ A, const u16* __restrict__ WT,
                                                 u16* __restrict__ VT) {
    __shared__ short As[128 * 40];
    __shared__ short Bs[128 * 40];
    const int m0 = blockIdx.y * 128, n0 = blockIdx.x * 128;
    f32x4 acc[4][4];
#pragma unroll
    for (int i = 0; i < 4; i++)
#pragma unroll
        for (int j = 0; j < 4; j++) acc[i][j] = 0;
    gemm_core<1>(nullptr, A, H_, WT, H_, H_, m0, n0, As, Bs, acc);
    const int lane = threadIdx.x & 63, wave = threadIdx.x >> 6;
    const int wy = wave >> 1, wx = wave & 1, mq = lane >> 4, ml = lane & 15;
#pragma unroll
    for (int mi = 0; mi < 4; mi++)
#pragma unroll
        for (int ni = 0; ni < 4; ni++) {
            const int n = n0 + wx * 64 + ni * 16 + ml;
            const int mbase = m0 + wy * 64 + mi * 16 + mq * 4;   // 4-aligned, same b for all 4
            const int b = mbase >> 10, s = mbase & 1023;
            ushort4 w;
            w.x = f2bf(acc[mi][ni][0]); w.y = f2bf(acc[mi][ni][1]);
            w.z = f2bf(acc[mi][ni][2]); w.w = f2bf(acc[mi][ni][3]);
            *(ushort4*)(VT + ((size_t)(b * 1024 + n)) * 1024 + s) = w;
        }
}

// ---------------- FUSED attention: QK^T + gauss + mask + softmax + qmask -> attn, then PV -> resB ----
// Block: 64 q-rows x full 1024 k-cols. 512 threads = 8 waves.
// QK phase: waves 2m x 4n; wave tile 32m x 256n; acc[mi 0..1][nf 0..15].
// PV phase: waves 2m x 4d; wave tile 32m x 64d; P staged in swizzled LDS, V streamed from VT.
__global__ __launch_bounds__(512, 2) void qk_sm_k(
    const u16* __restrict__ Qb, const u16* __restrict__ Kb,
    const void* __restrict__ mask, const float* __restrict__ gfac,
    const int* __restrict__ fl, const float* __restrict__ qmask,
    float* __restrict__ attn, const u16* __restrict__ VT, u16* __restrict__ resB)
{
    // LDS arena (152576 B):
    //   QK phase: As [0,2560) shorts, Bs [2560,43520)
    //   PV phase: Ps [0,65536) (swizzled bf16 64x1024), Vs [65536,75776) (256x40)
    //   red (epilogue reductions): shorts [75776,76288)
    __shared__ short smem[76288];
    short* As = smem;
    short* Bs = smem + 2560;
    short* Ps = smem;
    short* Vs = smem + 65536;
    float* red = (float*)(smem + 75776);   // [2][32][4] -> (wm*32+rr)*4 + wn

    // XCD-bijective swizzle: 512 blocks, contiguous 64-block chunk (4 full z) per XCD
    const int flat = blockIdx.x;
    const int wgid = (flat & 7) * 64 + (flat >> 3);
    const int z = wgid >> 4, m0 = (wgid & 15) * 64;
    const int h = z >> 3, b = z & 7;

    const u16* Aq = Qb + (size_t)b * S_ * H_ + h * D_;
    const u16* Bk = Kb + (size_t)b * S_ * H_ + h * D_;

    const int t = threadIdx.x;
    const int lane = t & 63, wave = t >> 6;
    const int wm = wave >> 2, wn = wave & 3;
    const int mq = lane >> 4, ml = lane & 15;

    f32x4 acc[2][16];
#pragma unroll
    for (int mi = 0; mi < 2; mi++)
#pragma unroll
        for (int nf = 0; nf < 16; nf++) acc[mi][nf] = 0;

    for (int k0 = 0; k0 < D_; k0 += 32) {
        __syncthreads();
        if (t < 256) {                               // stage A: 64 rows x 32 k
            const int row = t >> 2, kq = t & 3;
            *(s16x8*)(As + row * 40 + kq * 8) =
                *(const s16x8*)(Aq + (size_t)(m0 + row) * H_ + k0 + kq * 8);
        }
#pragma unroll
        for (int it = 0; it < 8; it++) {             // stage B: 1024 rows x 32 k
            const int c = it * 512 + t;
            const int row = c >> 2, kq = c & 3;
            *(s16x8*)(Bs + row * 40 + kq * 8) =
                *(const s16x8*)(Bk + (size_t)row * H_ + k0 + kq * 8);
        }
        __syncthreads();
        s16x8 af0 = *(s16x8*)(As + (wm * 32 + ml) * 40 + mq * 8);
        s16x8 af1 = *(s16x8*)(As + (wm * 32 + 16 + ml) * 40 + mq * 8);
#pragma unroll
        for (int g4 = 0; g4 < 4; g4++) {
            s16x8 bf4[4];
#pragma unroll
            for (int j = 0; j < 4; j++)
                bf4[j] = *(s16x8*)(Bs + (wn * 256 + (g4 * 4 + j) * 16 + ml) * 40 + mq * 8);
#pragma unroll
            for (int j = 0; j < 4; j++) {
                acc[0][g4 * 4 + j] = __builtin_amdgcn_mfma_f32_16x16x32_bf16(af0, bf4[j], acc[0][g4 * 4 + j], 0, 0, 0);
                acc[1][g4 * 4 + j] = __builtin_amdgcn_mfma_f32_16x16x32_bf16(af1, bf4[j], acc[1][g4 * 4 + j], 0, 0, 0);
            }
        }
    }

    // ---- epilogue 1: gauss + mask + softmax stats on register fragments ----
    const float ginv = 1.0f / gfac[0];
    const int code = fl[2];
    const size_t zrow = (size_t)z * S_;
    float rmax[2][4], rsum[2][4], scv[2][4];

#pragma unroll
    for (int mi = 0; mi < 2; mi++)
#pragma unroll
        for (int r = 0; r < 4; r++) {
            const int qg = m0 + wm * 32 + mi * 16 + mq * 4 + r;
            const size_t mbase = ((size_t)b * S_ + qg) * S_;
            float mx = -3.0e38f;
#pragma unroll
            for (int nf = 0; nf < 16; nf++) {
                const int kg = wn * 256 + nf * 16 + ml;
                float diff = (float)(qg - kg);
                float val = acc[mi][nf][r] * 0.0625f - diff * diff * ginv;
                int mv;
                if (code == 0)      mv = ((const unsigned char*)mask)[mbase + kg];
                else if (code == 1) mv = ((const int*)mask)[mbase + kg];
                else if (code == 2) mv = (((const u16*)mask)[mbase + kg] != 0);
                else                mv = (((const u32*)mask)[mbase + kg] != 0);
                if (mv) val = -4294967296.0f;
                acc[mi][nf][r] = val;
                mx = fmaxf(mx, val);
            }
            rmax[mi][r] = mx;
        }
#pragma unroll
    for (int o = 1; o < 16; o <<= 1)
#pragma unroll
        for (int mi = 0; mi < 2; mi++)
#pragma unroll
            for (int r = 0; r < 4; r++)
                rmax[mi][r] = fmaxf(rmax[mi][r], __shfl_xor(rmax[mi][r], o, 64));
    if (ml == 0)
#pragma unroll
        for (int mi = 0; mi < 2; mi++)
#pragma unroll
            for (int r = 0; r < 4; r++) red[(wm * 32 + mi * 16 + mq * 4 + r) * 4 + wn] = rmax[mi][r];
    __syncthreads();
#pragma unroll
    for (int mi = 0; mi < 2; mi++)
#pragma unroll
        for (int r = 0; r < 4; r++) {
            const float* rr = red + (wm * 32 + mi * 16 + mq * 4 + r) * 4;
            rmax[mi][r] = fmaxf(fmaxf(rr[0], rr[1]), fmaxf(rr[2], rr[3]));
        }
    __syncthreads();
#pragma unroll
    for (int mi = 0; mi < 2; mi++)
#pragma unroll
        for (int r = 0; r < 4; r++) {
            float s = 0.f;
#pragma unroll
            for (int nf = 0; nf < 16; nf++) {
                float p = __expf(acc[mi][nf][r] - rmax[mi][r]);
                acc[mi][nf][r] = p;
                s += p;
            }
            rsum[mi][r] = s;
        }
#pragma unroll
    for (int o = 1; o < 16; o <<= 1)
#pragma unroll
        for (int mi = 0; mi < 2; mi++)
#pragma unroll
            for (int r = 0; r < 4; r++) rsum[mi][r] += __shfl_xor(rsum[mi][r], o, 64);
    if (ml == 0)
#pragma unroll
        for (int mi = 0; mi < 2; mi++)
#pragma unroll
            for (int r = 0; r < 4; r++) red[(wm * 32 + mi * 16 + mq * 4 + r) * 4 + wn] = rsum[mi][r];
    __syncthreads();
#pragma unroll
    for (int mi = 0; mi < 2; mi++)
#pragma unroll
        for (int r = 0; r < 4; r++) {
            const float* rr = red + (wm * 32 + mi * 16 + mq * 4 + r) * 4;
            const int qg = m0 + wm * 32 + mi * 16 + mq * 4 + r;
            const float s = rr[0] + rr[1] + rr[2] + rr[3];
            scv[mi][r] = qmask[b * S_ + qg] / s;
        }

    // ---- store final attn (global, once) + stage P (bf16, swizzled) into LDS ----
    // NOTE: all waves passed the red barriers above, so QK-phase Bs reads are drained
    // before Ps (which aliases As/Bs) is overwritten.
#pragma unroll
    for (int mi = 0; mi < 2; mi++)
#pragma unroll
        for (int r = 0; r < 4; r++) {
            const int prow = wm * 32 + mi * 16 + mq * 4 + r;     // local q row 0..63
            const int qg = m0 + prow;
            float* gp = attn + (zrow + qg) * S_ + wn * 256 + ml;
            const float sc = scv[mi][r];
#pragma unroll
            for (int nf = 0; nf < 16; nf++) {
                const float v = acc[mi][nf][r] * sc;
                gp[nf * 16] = v;
                const int col = wn * 256 + nf * 16 + ml;
                Ps[prow * 1024 + (col ^ ((prow & 7) << 3))] = (short)f2bf(v);
            }
        }

    // ---- PV phase: res[64][256] = P @ V_h ----
    const int wr = wave >> 2, wc = wave & 3;       // 2m x 4d
    f32x4 acc2[2][4];
#pragma unroll
    for (int mi = 0; mi < 2; mi++)
#pragma unroll
        for (int ni = 0; ni < 4; ni++) acc2[mi][ni] = 0;

    const u16* Vp = VT + ((size_t)(b * 1024 + h * D_)) * 1024;
    for (int k0 = 0; k0 < S_; k0 += 32) {
        {   // stage V: 256 d-rows x 32 k
            const int row = t >> 1, half = t & 1;
            const u16* s = Vp + (size_t)row * 1024 + k0 + half * 16;
            short* dpt = Vs + row * 40 + half * 16;
            *(s16x8*)dpt       = *(const s16x8*)s;
            *(s16x8*)(dpt + 8) = *(const s16x8*)(s + 8);
        }
        __syncthreads();
        s16x8 pa[2];
#pragma unroll
        for (int mi = 0; mi < 2; mi++) {
            const int prow = wr * 32 + mi * 16 + ml;
            pa[mi] = *(s16x8*)(Ps + prow * 1024 + ((((k0 >> 3) + mq) ^ (prow & 7)) << 3));
        }
#pragma unroll
        for (int ni = 0; ni < 4; ni++) {
            s16x8 vf = *(s16x8*)(Vs + (wc * 64 + ni * 16 + ml) * 40 + mq * 8);
            acc2[0][ni] = __builtin_amdgcn_mfma_f32_16x16x32_bf16(pa[0], vf, acc2[0][ni], 0, 0, 0);
            acc2[1][ni] = __builtin_amdgcn_mfma_f32_16x16x32_bf16(pa[1], vf, acc2[1][ni], 0, 0, 0);
        }
        __syncthreads();
    }

    // ---- epilogue 2: store res bf16 ----
    u16* C = resB + (size_t)b * S_ * H_ + h * D_;
#pragma unroll
    for (int mi = 0; mi < 2; mi++)
#pragma unroll
        for (int ni = 0; ni < 4; ni++) {
            const int n = wc * 64 + ni * 16 + ml;
#pragma unroll
            for (int r = 0; r < 4; r++) {
                const int m = m0 + wr * 32 + mi * 16 + mq * 4 + r;
                C[(size_t)m * H_ + n] = f2bf(acc2[mi][ni][r]);
            }
        }
}

// ---------------- final: tmp[m][n] bf16 = [dec|res] @ WfT^T + bf + dec ----------------
__global__ __launch_bounds__(256) void final_mfma_k(const float* __restrict__ dec, const u16* __restrict__ resB,
                                                    const u16* __restrict__ WfT, const float* __restrict__ bfv,
                                                    u16* __restrict__ tmp) {
    __shared__ short As[128 * 40];
    __shared__ short Bs[128 * 40];
    const int m0 = blockIdx.y * 128, n0 = blockIdx.x * 128;
    f32x4 acc[4][4];
#pragma unroll
    for (int i = 0; i < 4; i++)
#pragma unroll
        for (int j = 0; j < 4; j++) acc[i][j] = 0;
    gemm_core<2>(dec, resB, H_, WfT, 2048, 2048, m0, n0, As, Bs, acc);
    const int lane = threadIdx.x & 63, wave = threadIdx.x >> 6;
    const int wy = wave >> 1, wx = wave & 1, mq = lane >> 4, ml = lane & 15;
#pragma unroll
    for (int mi = 0; mi < 4; mi++)
#pragma unroll
        for (int ni = 0; ni < 4; ni++) {
            const int n = n0 + wx * 64 + ni * 16 + ml;
#pragma unroll
            for (int r = 0; r < 4; r++) {
                const int m = m0 + wy * 64 + mi * 16 + mq * 4 + r;
                float val = acc[mi][ni][r] + bfv[n] + dec[(size_t)m * H_ + n];
                tmp[(size_t)m * H_ + n] = f2bf(val);
            }
        }
}

// ---------------- LayerNorm (bf16 tmp -> fp32 out) ----------------
__global__ __launch_bounds__(256) void ln2_k(const u16* __restrict__ tmp, const float* __restrict__ gm,
                                             const float* __restrict__ bt, float* __restrict__ out) {
    const int m = blockIdx.x, t = threadIdx.x;
    ushort4 u = ((const ushort4*)(tmp + (size_t)m * H_))[t];
    float xa[4] = {bf2f(u.x), bf2f(u.y), bf2f(u.z), bf2f(u.w)};
    float s = 0.f, s2 = 0.f;
#pragma unroll
    for (int i = 0; i < 4; i++) { s += xa[i]; s2 += xa[i] * xa[i]; }
#pragma unroll
    for (int o = 32; o; o >>= 1) { s += __shfl_xor(s, o, 64); s2 += __shfl_xor(s2, o, 64); }
    __shared__ float rs[4], rs2[4];
    if ((t & 63) == 0) { rs[t >> 6] = s; rs2[t >> 6] = s2; }
    __syncthreads();
    s  = rs[0] + rs[1] + rs[2] + rs[3];
    s2 = rs2[0] + rs2[1] + rs2[2] + rs2[3];
    float mu = s * (1.f / 1024.f);
    float var = s2 * (1.f / 1024.f) - mu * mu;
    float rstd = rsqrtf(var + 1e-5f);
    float ov[4];
#pragma unroll
    for (int i = 0; i < 4; i++) {
        int n = t * 4 + i;
        ov[i] = (xa[i] - mu) * rstd * gm[n] + bt[n];
    }
    *(float4*)(out + (size_t)m * H_ + t * 4) = make_float4(ov[0], ov[1], ov[2], ov[3]);
}

extern "C" void kernel_launch(void* const* d_in, const int* in_sizes, int n_in,
                              void* d_out, int out_size, void* d_ws, size_t ws_size,
                              hipStream_t stream) {
    const float* memory = (const float*)d_in[0];
    const float* dec    = (const float*)d_in[1];
    const void*  mask   = d_in[2];
    const float* qmask  = (const float*)d_in[3];
    const float* Wk     = (const float*)d_in[4];
    const float* Wv     = (const float*)d_in[5];
    const float* Wq     = (const float*)d_in[6];
    const float* Wf     = (const float*)d_in[7];
    const float* bfv    = (const float*)d_in[8];
    const float* gamma  = (const float*)d_in[9];
    const float* beta   = (const float*)d_in[10];
    const float* gfac   = (const float*)d_in[11];

    // ---- workspace layout (peak 59 MiB) ----
    // [0,1M) flags | [1,3) WqT | [3,5) WkT | [5,7) WvT | [7,11) WfT
    // [11,27) Qb bf16  (tmp bf16 aliases after attn)
    // [27,43) Kb bf16
    // [43,59) VT bf16
    char* ws = (char*)d_ws;
    int* fl  = (int*)ws;
    u16* WqT = (u16*)(ws + (1u  << 20));
    u16* WkT = (u16*)(ws + (3u  << 20));
    u16* WvT = (u16*)(ws + (5u  << 20));
    u16* WfT = (u16*)(ws + (7u  << 20));
    u16* Qb  = (u16*)(ws + (11u << 20));
    u16* Kb  = (u16*)(ws + (27u << 20));
    u16* VT  = (u16*)(ws + (43u << 20));
    u16* tmpB = Qb;          // Qb dead after qk_sm_k

    float* out   = (float*)d_out;
    float* attnF = out + (size_t)B_ * S_ * H_;   // final attn written once by qk_sm_k

    // resB lives in the `out` region of d_out (32 MiB): written by qk_sm_k's PV phase,
    // read by final_mfma_k, then overwritten by ln2_k (stream-ordered, no overlap in time).
    u16* resB = (u16*)out;

    // bf16 pre-casts live in the attn region of d_out (dead once qk_sm_k writes attn)
    u16* memB = (u16*)attnF;
    u16* decB = memB + (size_t)B_ * S_ * H_;

    init_flags_k<<<1, 1, 0, stream>>>(fl);
    or_mask_k<<<256, 256, 0, stream>>>((const u32*)mask, fl);
    classify_mask_k<<<1, 1, 0, stream>>>(fl);

    tcast_k<<<dim3(32, 32), 256, 0, stream>>>(Wq, WqT, 1024, 1024);
    tcast_k<<<dim3(32, 32), 256, 0, stream>>>(Wk, WkT, 1024, 1024);
    tcast_k<<<dim3(32, 32), 256, 0, stream>>>(Wv, WvT, 1024, 1024);
    tcast_k<<<dim3(32, 64), 256, 0, stream>>>(Wf, WfT, 2048, 1024);

    castbf_k<<<8192, 256, 0, stream>>>(memory, memB);
    castbf_k<<<8192, 256, 0, stream>>>(dec,    decB);

    gemm_proj_k<<<dim3(8, 64), 256, 0, stream>>>(decB, WqT, Qb);
    gemm_proj_k<<<dim3(8, 64), 256, 0, stream>>>(memB, WkT, Kb);
    gemm_vt_k  <<<dim3(8, 64), 256, 0, stream>>>(memB, WvT, VT);

    qk_sm_k<<<512, 512, 0, stream>>>(Qb, Kb, mask, gfac, fl, qmask, attnF, VT, resB);
    final_mfma_k<<<dim3(8, 64), 256, 0, stream>>>(dec, resB, WfT, bfv, tmpB);
    ln2_k<<<M_, 256, 0, stream>>>(tmpB, gamma, beta, out);
}